// Round 4
// baseline (542.023 us; speedup 1.0000x reference)
//
#include <hip/hip_runtime.h>
#include <hip/hip_fp16.h>

// ResidualDenoiser megakernel: cvt -> L0 -> L1 -> L2 -> L3(splitK) -> softmax
// in ONE dispatch with device-scope grid barriers (512 blocks, all co-resident
// by __launch_bounds__(256,2) + 32 KB LDS => >=2 blocks/CU guaranteed).
//
// Activations in persistent fp16 buffer H[8192][3328] = [A3|A2|A1|A0=x]:
//   layer0: in H+3072 (K= 256) -> out cols 2048:3072
//   layer1: in H+2048 (K=1280) -> out cols 1024:2048
//   layer2: in H+1024 (K=2304) -> out cols    0:1024
//   layer3: in H+0    (K=3328) -> splitK=4 atomicAdd fp32 into out (bias
//           pre-applied), then ragged segment softmax in place.
// GEMM tile: BM=BN=128, BK=64, 4 waves (2x2) each 64x64, 16x16x32 f16 MFMA
// (R2's measured-best per-layer config: 32 FLOP per LDS byte).

#define LDH 3328
#define NROWS 8192
#define NBLK 512

typedef _Float16 f16x8 __attribute__((ext_vector_type(8)));
typedef _Float16 f16x4 __attribute__((ext_vector_type(4)));
typedef float f32x4 __attribute__((ext_vector_type(4)));

__constant__ int c_bnd[11] = {0, 2, 5, 10, 18, 31, 52, 86, 141, 230, 256};

// async global->LDS, 16B per lane; LDS dest is wave-uniform base + lane*16.
__device__ __forceinline__ void async_cp16(const _Float16* g, _Float16* l) {
  __builtin_amdgcn_global_load_lds(
      (__attribute__((address_space(1))) void*)g,
      (__attribute__((address_space(3))) void*)l, 16, 0, 0);
}

__device__ __forceinline__ _Float16 f2h(float f) { return (_Float16)f; }

// grid barrier: monotonic counter, device scope. All NBLK blocks co-resident.
__device__ __forceinline__ void gridbar(unsigned* c, unsigned target) {
  __syncthreads();
  if (threadIdx.x == 0) {
    __threadfence();  // release: flush this XCD's dirty L2 lines
    atomicAdd(c, 1u); // device-scope (m20)
    while (__hip_atomic_load(c, __ATOMIC_RELAXED, __HIP_MEMORY_SCOPE_AGENT) <
           target)
      __builtin_amdgcn_s_sleep(8);
    __threadfence();  // acquire: invalidate caches before reading peers' data
  }
  __syncthreads();
}

__global__ void zero_kernel(unsigned* c) { *c = 0u; }

// ---------------------------------------------------------------------------
// GEMM phase: one 128x128 tile per block. C = A[128,K-span] @ W[N,K]^T.
// NCB = column blocks (N/128). splitK = 512/(64*NCB) slices of kSpan each.
// FUSE=1: out fp16 = relu(acc*alpha+beta) into H. FUSE=0: atomicAdd into outF.
template <int FUSE, int NCB>
__device__ __forceinline__ void gemm_phase(
    unsigned char* smem, const _Float16* __restrict__ A, int ldA, int K,
    int kSpan, const _Float16* __restrict__ W, const float* __restrict__ bias,
    const float* __restrict__ g, const float* __restrict__ be,
    const float* __restrict__ rm, const float* __restrict__ rv,
    _Float16* __restrict__ outH, int outOff, float* __restrict__ outF,
    int ldF) {
  _Float16* Alds = (_Float16*)smem;            // 128*64 fp16 = 16 KB
  _Float16* Blds = (_Float16*)(smem + 16384);  // 128*64 fp16 = 16 KB

  const int tid = threadIdx.x;
  const int lane = tid & 63;
  const int wave = tid >> 6;  // 0..3
  const int wr = wave >> 1;   // 64-row half
  const int wc = wave & 1;    // 64-col half
  const int t = blockIdx.x;   // 512 tiles: 64 row x NCB col x splitK
  const int bx = t & 63;
  const int rest = t >> 6;
  const int cb = rest % NCB;
  const int ks = rest / NCB;
  const int row0 = bx * 128;
  const int col0 = cb * 128;
  const int k0b = ks * kSpan;
  const int k0e = k0b + kSpan;
  const int lr = lane >> 3;  // staging: 8 rows x 8 16B-chunks
  const int ls = lane & 7;
  const int lc = ls ^ lr;    // XOR swizzle (bank-conflict-free b128 reads)
  const int fr = lane & 15;  // fragment row/col
  const int q = lane >> 4;   // quad

  f32x4 acc[4][4] = {};

  for (int k0 = k0b; k0 < k0e; k0 += 64) {
    __syncthreads();
#pragma unroll
    for (int it = 0; it < 4; ++it) {
      const int rl = it * 32 + wave * 8;
      async_cp16(A + (size_t)(row0 + rl + lr) * ldA + k0 + lc * 8,
                 &Alds[rl * 64]);
      async_cp16(W + (size_t)(col0 + rl + lr) * K + k0 + lc * 8,
                 &Blds[rl * 64]);
    }
    __syncthreads();

#pragma unroll
    for (int kq = 0; kq < 2; ++kq) {
      f16x8 av[4], bv[4];
#pragma unroll
      for (int tt = 0; tt < 4; ++tt) {
        const int ra = wr * 64 + tt * 16 + fr;
        av[tt] =
            *(const f16x8*)&Alds[ra * 64 + (((q + 4 * kq) ^ (ra & 7)) * 8)];
        const int rb = wc * 64 + tt * 16 + fr;
        bv[tt] =
            *(const f16x8*)&Blds[rb * 64 + (((q + 4 * kq) ^ (rb & 7)) * 8)];
      }
#pragma unroll
      for (int tm = 0; tm < 4; ++tm)
#pragma unroll
        for (int tn = 0; tn < 4; ++tn)
          acc[tm][tn] = __builtin_amdgcn_mfma_f32_16x16x32_f16(
              av[tm], bv[tn], acc[tm][tn], 0, 0, 0);
    }
  }

  // Epilogue. C/D layout: col = lane&15, row = (lane>>4)*4 + reg.
#pragma unroll
  for (int tn = 0; tn < 4; ++tn) {
    const int n = col0 + wc * 64 + tn * 16 + fr;
    if constexpr (FUSE == 1) {
      const float alpha = g[n] * rsqrtf(rv[n] + 1e-5f);
      const float beta = (bias[n] - rm[n]) * alpha + be[n];
#pragma unroll
      for (int tm = 0; tm < 4; ++tm) {
        const int rbase = row0 + wr * 64 + tm * 16 + q * 4;
#pragma unroll
        for (int r = 0; r < 4; ++r) {
          float v = acc[tm][tn][r] * alpha + beta;
          v = fmaxf(v, 0.0f);
          outH[(size_t)(rbase + r) * LDH + outOff + n] = f2h(v);
        }
      }
    } else {
#pragma unroll
      for (int tm = 0; tm < 4; ++tm) {
        const int rbase = row0 + wr * 64 + tm * 16 + q * 4;
#pragma unroll
        for (int r = 0; r < 4; ++r)
          atomicAdd(&outF[(size_t)(rbase + r) * ldF + n], acc[tm][tn][r]);
      }
    }
  }
}

// ---------------------------------------------------------------------------
__launch_bounds__(256, 2) __global__ void mega_kernel(
    const float* __restrict__ x, const float* __restrict__ W0,
    const float* __restrict__ b0, const float* __restrict__ g0,
    const float* __restrict__ be0, const float* __restrict__ rm0,
    const float* __restrict__ rv0, const float* __restrict__ W1,
    const float* __restrict__ b1, const float* __restrict__ g1,
    const float* __restrict__ be1, const float* __restrict__ rm1,
    const float* __restrict__ rv1, const float* __restrict__ W2,
    const float* __restrict__ b2, const float* __restrict__ g2,
    const float* __restrict__ be2, const float* __restrict__ rm2,
    const float* __restrict__ rv2, const float* __restrict__ W3,
    const float* __restrict__ b3, const int* __restrict__ seg,
    float* __restrict__ out, _Float16* __restrict__ H,
    _Float16* __restrict__ Wh0, _Float16* __restrict__ Wh1,
    _Float16* __restrict__ Wh2, _Float16* __restrict__ Wh3, unsigned* cnt) {
  __shared__ __align__(16) unsigned char smem[32768];
  const int tid = threadIdx.x;

  // ---- phase 0: weight fp32->fp16 cvt + x stage + out=bias init ----
  {
    // cumulative float4 counts
    const int n0 = 65536;            // W0
    const int n1 = n0 + 327680;      // W1
    const int n2 = n1 + 589824;      // W2
    const int n3 = n2 + 212992;      // W3
    const int n4 = n3 + 524288;      // x
    const int n5 = n4 + 524288;      // out init
    for (int i = blockIdx.x * 256 + tid; i < n5; i += NBLK * 256) {
      if (i < n3) {
        const float* s;
        _Float16* d;
        if (i < n0) {
          s = W0; d = Wh0;
        } else if (i < n1) {
          s = W1 - (size_t)n0 * 4; d = Wh1 - (size_t)n0 * 4;
        } else if (i < n2) {
          s = W2 - (size_t)n1 * 4; d = Wh2 - (size_t)n1 * 4;
        } else {
          s = W3 - (size_t)n2 * 4; d = Wh3 - (size_t)n2 * 4;
        }
        const float4 v = *(const float4*)&s[(size_t)i * 4];
        f16x4 h = {f2h(v.x), f2h(v.y), f2h(v.z), f2h(v.w)};
        *(f16x4*)&d[(size_t)i * 4] = h;
      } else if (i < n4) {
        const int j = i - n3;
        const int row = j >> 6;
        const int c = (j & 63) * 4;
        const float4 v = *(const float4*)&x[(size_t)j * 4];
        f16x4 h = {f2h(v.x), f2h(v.y), f2h(v.z), f2h(v.w)};
        *(f16x4*)&H[(size_t)row * LDH + 3072 + c] = h;
      } else {
        const int j = i - n4;
        const int c = (j & 63) * 4;
        *(float4*)&out[(size_t)j * 4] = *(const float4*)&b3[c];
      }
    }
  }
  gridbar(cnt, 1 * NBLK);

  // ---- GEMM layers ----
  gemm_phase<1, 8>(smem, H + 3072, LDH, 256, 256, Wh0, b0, g0, be0, rm0, rv0,
                   H, 2048, nullptr, 0);
  gridbar(cnt, 2 * NBLK);
  gemm_phase<1, 8>(smem, H + 2048, LDH, 1280, 1280, Wh1, b1, g1, be1, rm1,
                   rv1, H, 1024, nullptr, 0);
  gridbar(cnt, 3 * NBLK);
  gemm_phase<1, 8>(smem, H + 1024, LDH, 2304, 2304, Wh2, b2, g2, be2, rm2,
                   rv2, H, 0, nullptr, 0);
  gridbar(cnt, 4 * NBLK);
  // layer3: N=256 -> NCB=2, splitK=4 (kSpan = 3328/4 = 832)
  gemm_phase<0, 2>(smem, H, LDH, 3328, 832, Wh3, nullptr, nullptr, nullptr,
                   nullptr, nullptr, nullptr, 0, out, 256);
  gridbar(cnt, 5 * NBLK);

  // ---- ragged segment softmax, 16 rows per block (4 batches x 4 waves) ----
  {
    float(*vals)[256] = (float(*)[256])smem;
    float(*red)[16] = (float(*)[16])(smem + 4096 + 128);
    const int w = tid >> 6;
    const int l = tid & 63;
    const int4 s4 = *(const int4*)&seg[l * 4];
#pragma unroll 1
    for (int batch = 0; batch < 4; ++batch) {
      const int row = blockIdx.x * 16 + batch * 4 + w;
      __syncthreads();
      float4 v = *(float4*)&out[(size_t)row * 256 + l * 4];
      *(float4*)&vals[w][l * 4] = v;
      __syncthreads();
      if (l < 10) {
        float m = -1e30f;
        for (int j = c_bnd[l]; j < c_bnd[l + 1]; ++j) m = fmaxf(m, vals[w][j]);
        red[w][l] = m;
      }
      __syncthreads();
      float4 e;
      e.x = expf(v.x - red[w][s4.x]);
      e.y = expf(v.y - red[w][s4.y]);
      e.z = expf(v.z - red[w][s4.z]);
      e.w = expf(v.w - red[w][s4.w]);
      *(float4*)&vals[w][l * 4] = e;
      __syncthreads();
      if (l < 10) {
        float s = 0.0f;
        for (int j = c_bnd[l]; j < c_bnd[l + 1]; ++j) s += vals[w][j];
        red[w][l] = s;
      }
      __syncthreads();
      float4 o;
      o.x = e.x / red[w][s4.x];
      o.y = e.y / red[w][s4.y];
      o.z = e.z / red[w][s4.z];
      o.w = e.w / red[w][s4.w];
      *(float4*)&out[(size_t)row * 256 + l * 4] = o;
    }
  }
}

// ---------------------------------------------------------------------------
extern "C" void kernel_launch(void* const* d_in, const int* in_sizes, int n_in,
                              void* d_out, int out_size, void* d_ws,
                              size_t ws_size, hipStream_t stream) {
  const float* x = (const float*)d_in[0];
  const float* W0 = (const float*)d_in[1];
  const float* b0 = (const float*)d_in[2];
  const float* g0 = (const float*)d_in[3];
  const float* be0 = (const float*)d_in[4];
  const float* rm0 = (const float*)d_in[5];
  const float* rv0 = (const float*)d_in[6];
  const float* W1 = (const float*)d_in[7];
  const float* b1 = (const float*)d_in[8];
  const float* g1 = (const float*)d_in[9];
  const float* be1 = (const float*)d_in[10];
  const float* rm1 = (const float*)d_in[11];
  const float* rv1 = (const float*)d_in[12];
  const float* W2 = (const float*)d_in[13];
  const float* b2 = (const float*)d_in[14];
  const float* g2 = (const float*)d_in[15];
  const float* be2 = (const float*)d_in[16];
  const float* rm2 = (const float*)d_in[17];
  const float* rv2 = (const float*)d_in[18];
  const float* W3 = (const float*)d_in[19];
  const float* b3 = (const float*)d_in[20];
  const int* seg = (const int*)d_in[21];
  float* out = (float*)d_out;

  // ws (fp16): H[8192*3328] | Wh0 | Wh1 | Wh2 | Wh3 | counter  (~64.1 MB)
  _Float16* H = (_Float16*)d_ws;
  size_t off = (size_t)NROWS * LDH;
  _Float16* Wh0 = H + off; off += 1024 * 256;
  _Float16* Wh1 = H + off; off += 1024 * 1280;
  _Float16* Wh2 = H + off; off += 1024 * 2304;
  _Float16* Wh3 = H + off; off += 256 * 3328;
  unsigned* cnt = (unsigned*)(H + off);

  zero_kernel<<<1, 1, 0, stream>>>(cnt);
  mega_kernel<<<NBLK, 256, 0, stream>>>(
      x, W0, b0, g0, be0, rm0, rv0, W1, b1, g1, be1, rm1, rv1, W2, b2, g2,
      be2, rm2, rv2, W3, b3, seg, out, H, Wh0, Wh1, Wh2, Wh3, cnt);
}